// Round 6
// baseline (26226.608 us; speedup 1.0000x reference)
//
#include <hip/hip_runtime.h>

typedef short short8 __attribute__((ext_vector_type(8)));
typedef float v4f   __attribute__((ext_vector_type(4)));

#define N_NODES 50000
#define N_EDGES 1600000
#define DIM     512
#define NCB     13        // col blocks: col>>12, 0..12 (4096-row window = 4MB = L2/XCD)
#define NWAVE   8192      // phase waves (2048 blocks * 4)
#define NK      7         // nodes per wave: ceil(50000/8192); k = node>>13
#define NKEYS   106496    // NCB * NWAVE
#define SCAN_NB 104       // 104 * 1024 = 106496 exactly

__device__ __forceinline__ float bf2f(unsigned short u) {
    unsigned int x = ((unsigned int)u) << 16;
    return __uint_as_float(x);
}
__device__ __forceinline__ unsigned int f2bfu(float f) {
    unsigned int x = __float_as_uint(f);
    unsigned int r = x + 0x7fffu + ((x >> 16) & 1u);   // RTNE
    return r >> 16;
}
__device__ __forceinline__ float lo16(unsigned int u) { return __uint_as_float(u << 16); }
__device__ __forceinline__ float hi16(unsigned int u) { return __uint_as_float(u & 0xffff0000u); }

__device__ __forceinline__ int edge_key(int r, int c) {
    // (colblock, waveslot): gather wave w handles run [start[cb*NWAVE+w], start[cb*NWAVE+w+1])
    return (c >> 12) * NWAVE + (r & (NWAVE - 1));
}

__device__ __forceinline__ void gload_lds16(const void* g, void* l) {
    __builtin_amdgcn_global_load_lds(
        (const __attribute__((address_space(1))) unsigned int*)g,
        (__attribute__((address_space(3))) unsigned int*)l, 16, 0, 0);
}

// ---------------- dtype detection --------------------------------------------
__global__ void detect_kernel(const unsigned int* __restrict__ xw,
                              const int* __restrict__ erow,
                              int* __restrict__ flags) {
    __shared__ int cbf, cz;
    if (threadIdx.x == 0) { cbf = 0; cz = 0; }
    __syncthreads();
    int lb = 0, lz = 0;
    for (int i = threadIdx.x; i < 1024; i += 256) {
        unsigned int w = xw[i];
        unsigned int e0 = (w >> 7) & 0xFFu;
        unsigned int e1 = (w >> 23) & 0xFFu;
        if (e0 >= 0x70u && e0 <= 0x8Fu && e1 >= 0x70u && e1 <= 0x8Fu) lb++;
        if (erow[2 * i + 1] == 0) lz++;
    }
    atomicAdd(&cbf, lb);
    atomicAdd(&cz, lz);
    __syncthreads();
    if (threadIdx.x == 0) {
        flags[0] = (cbf > 512) ? 1 : 0;
        flags[1] = (cz > 512) ? 1 : 0;
    }
}

// ---------------- X fp32 -> bf16 pre-convert ----------------------------------
__global__ __launch_bounds__(256) void convert_x(const void* __restrict__ Xv,
                                                 unsigned short* __restrict__ Xc,
                                                 const int* __restrict__ flags) {
    if (flags[0] != 0) return;
    const float* Xf = (const float*)Xv;
    size_t i = ((size_t)blockIdx.x * 256 + threadIdx.x) * 8;
    float4 f0 = *(const float4*)(Xf + i);
    float4 f1 = *(const float4*)(Xf + i + 4);
    uint4 o;
    o.x = f2bfu(f0.x) | (f2bfu(f0.y) << 16);
    o.y = f2bfu(f0.z) | (f2bfu(f0.w) << 16);
    o.z = f2bfu(f1.x) | (f2bfu(f1.y) << 16);
    o.w = f2bfu(f1.z) | (f2bfu(f1.w) << 16);
    *(uint4*)(Xc + i) = o;
}

// ---------------- W transpose -> canonical bf16 Wt[n][k] = W[k][n] ------------
__global__ void transpose_w(const void* __restrict__ Wv,
                            unsigned short* __restrict__ Wt,
                            const int* __restrict__ flags) {
    __shared__ unsigned short tile[32][33];
    const bool fb = flags[0] != 0;
    int bx = blockIdx.x * 32, by = blockIdx.y * 32;
    int tx = threadIdx.x, ty = threadIdx.y;
    if (fb) {
        const unsigned short* W = (const unsigned short*)Wv;
        for (int r = ty; r < 32; r += 8)
            tile[r][tx] = W[(by + r) * DIM + bx + tx];
    } else {
        const float* W = (const float*)Wv;
        for (int r = ty; r < 32; r += 8)
            tile[r][tx] = (unsigned short)f2bfu(W[(by + r) * DIM + bx + tx]);
    }
    __syncthreads();
    for (int r = ty; r < 32; r += 8)
        Wt[(bx + r) * DIM + by + tx] = tile[tx][r];
}

// ---------------- GEMM: hidden = X @ W  (m97 structure: global_load_lds) ------
#define TM 128
#define TN 128
#define BK 32

__global__ __launch_bounds__(256) void gemm_kernel(
        const void* __restrict__ Xv,
        const unsigned short* __restrict__ Xc,
        const int have_xc,
        const unsigned short* __restrict__ Wt,
        unsigned short* __restrict__ H,
        const int* __restrict__ flags) {
    __shared__ unsigned short lA[TM * BK];
    __shared__ unsigned short lB[TN * BK];

    const bool fb = flags[0] != 0;
    const bool bfp = fb || (have_xc != 0);
    const unsigned short* Xb = fb ? (const unsigned short*)Xv : Xc;
    const float*          Xf = (const float*)Xv;

    const int t = threadIdx.x;
    const int mBase = blockIdx.y * TM;
    const int nBase = blockIdx.x * TN;
    const int w = t >> 6, lane = t & 63;
    const int lr = lane & 15, quad = lane >> 4;
    const int wr = w >> 1, wc = w & 1;

    v4f acc[4][4];
    #pragma unroll
    for (int i = 0; i < 4; ++i)
        #pragma unroll
        for (int j = 0; j < 4; ++j) acc[i][j] = (v4f)0.0f;

    for (int k0 = 0; k0 < DIM; k0 += BK) {
        #pragma unroll
        for (int r = 0; r < 2; ++r) {
            int chunk = w * 2 + r;
            int row = chunk * 16 + (lane >> 2);
            const unsigned short* gB = Wt + (size_t)(nBase + row) * DIM + k0 + (lane & 3) * 8;
            gload_lds16(gB, lB + chunk * 512);
        }
        if (bfp) {
            #pragma unroll
            for (int r = 0; r < 2; ++r) {
                int chunk = w * 2 + r;
                int row = chunk * 16 + (lane >> 2);
                int grow = mBase + row; if (grow >= N_NODES) grow = N_NODES - 1;
                const unsigned short* gA = Xb + (size_t)grow * DIM + k0 + (lane & 3) * 8;
                gload_lds16(gA, lA + chunk * 512);
            }
        } else {
            #pragma unroll
            for (int rep = 0; rep < 2; ++rep) {
                int idx = rep * 256 + t;
                int r = idx >> 2;
                int cc = (idx & 3) * 8;
                int grow = mBase + r; if (grow >= N_NODES) grow = N_NODES - 1;
                size_t goff = (size_t)grow * DIM + k0 + cc;
                float4 a0 = *(const float4*)(Xf + goff);
                float4 a1 = *(const float4*)(Xf + goff + 4);
                uint4 av;
                av.x = f2bfu(a0.x) | (f2bfu(a0.y) << 16);
                av.y = f2bfu(a0.z) | (f2bfu(a0.w) << 16);
                av.z = f2bfu(a1.x) | (f2bfu(a1.y) << 16);
                av.w = f2bfu(a1.z) | (f2bfu(a1.w) << 16);
                *(uint4*)(&lA[r * BK + cc]) = av;
            }
        }
        __syncthreads();

        short8 bfr[4];
        #pragma unroll
        for (int j = 0; j < 4; ++j)
            bfr[j] = *(const short8*)(&lB[(wc * 64 + j * 16 + lr) * BK + quad * 8]);
        #pragma unroll
        for (int i = 0; i < 4; ++i) {
            short8 a = *(const short8*)(&lA[(wr * 64 + i * 16 + lr) * BK + quad * 8]);
            #pragma unroll
            for (int j = 0; j < 4; ++j)
                acc[i][j] = __builtin_amdgcn_mfma_f32_16x16x32_bf16(a, bfr[j], acc[i][j], 0, 0, 0);
        }
        __syncthreads();
    }

    #pragma unroll
    for (int i = 0; i < 4; ++i) {
        #pragma unroll
        for (int j = 0; j < 4; ++j) {
            #pragma unroll
            for (int r = 0; r < 4; ++r) {
                int gm = mBase + wr * 64 + i * 16 + quad * 4 + r;
                int gn = nBase + wc * 64 + j * 16 + lr;
                if (gm < N_NODES)
                    H[(size_t)gm * DIM + gn] = (unsigned short)f2bfu(acc[i][j][r]);
            }
        }
    }
}

// ---------------- counting sort on key=(cb, waveslot) -------------------------
__global__ void hist_kernel(const int* __restrict__ row, const int* __restrict__ col,
                            int* __restrict__ cnt,
                            const int* __restrict__ flags) {
    const bool f64 = flags[1] != 0;
    int i = blockIdx.x * 256 + threadIdx.x;
    if (i < N_EDGES) {
        int r = f64 ? ((const int2*)row)[i].x : row[i];
        int c = f64 ? ((const int2*)col)[i].x : col[i];
        atomicAdd(&cnt[edge_key(r, c)], 1);
    }
}

__global__ __launch_bounds__(256) void scan1_kernel(const int* __restrict__ cnt,
                                                    int* __restrict__ bsum) {
    __shared__ int sh[256];
    const int b = blockIdx.x, t = threadIdx.x;
    int base = b * 1024 + t * 4;
    int s = 0;
    #pragma unroll
    for (int k = 0; k < 4; ++k) {
        int i = base + k;
        if (i < NKEYS) s += cnt[i];
    }
    sh[t] = s;
    __syncthreads();
    for (int off = 128; off > 0; off >>= 1) {
        if (t < off) sh[t] += sh[t + off];
        __syncthreads();
    }
    if (t == 0) bsum[b] = sh[0];
}

// scan2: exclusive prefix over the 104 block sums (single block, 1/thread)
__global__ __launch_bounds__(256) void scan2_kernel(int* __restrict__ bsum) {
    __shared__ int sh[256];
    const int t = threadIdx.x;
    int v = (t < SCAN_NB) ? bsum[t] : 0;
    sh[t] = v;
    __syncthreads();
    for (int off = 1; off < 256; off <<= 1) {
        int x = (t >= off) ? sh[t - off] : 0;
        __syncthreads();
        sh[t] += x;
        __syncthreads();
    }
    if (t < SCAN_NB) bsum[t] = sh[t] - v;   // exclusive
}

__global__ __launch_bounds__(256) void scan3_kernel(const int* __restrict__ cnt,
                                                    const int* __restrict__ bsum,
                                                    int* __restrict__ start,
                                                    int* __restrict__ cursor) {
    __shared__ int sh[256];
    const int b = blockIdx.x, t = threadIdx.x;
    if (b == 0 && t == 0) start[NKEYS] = N_EDGES;
    int boffs = bsum[b];
    int base = b * 1024 + t * 4;
    int v[4];
    #pragma unroll
    for (int k = 0; k < 4; ++k) {
        int i = base + k;
        v[k] = (i < NKEYS) ? cnt[i] : 0;
    }
    int tsum = v[0] + v[1] + v[2] + v[3];
    sh[t] = tsum;
    __syncthreads();
    for (int off = 1; off < 256; off <<= 1) {
        int x = (t >= off) ? sh[t - off] : 0;
        __syncthreads();
        sh[t] += x;
        __syncthreads();
    }
    int excl = sh[t] - tsum + boffs;
    #pragma unroll
    for (int k = 0; k < 4; ++k) {
        int i = base + k;
        if (i < NKEYS) { start[i] = excl; cursor[i] = excl; }
        excl += v[k];
    }
}

__global__ void scatter_kernel(const int* __restrict__ row, const int* __restrict__ col,
                               const void* __restrict__ valv,
                               int* __restrict__ cursor,
                               int2* __restrict__ sCV,
                               const int* __restrict__ flags) {
    const bool fb  = flags[0] != 0;
    const bool f64 = flags[1] != 0;
    int i = blockIdx.x * 256 + threadIdx.x;
    if (i < N_EDGES) {
        int r = f64 ? ((const int2*)row)[i].x : row[i];
        int c = f64 ? ((const int2*)col)[i].x : col[i];
        float v = fb ? bf2f(((const unsigned short*)valv)[i])
                     : ((const float*)valv)[i];
        int p = atomicAdd(&cursor[edge_key(r, c)], 1);
        int2 cv;
        cv.x = c | ((r >> 13) << 16);     // col in [0,50000) fits 16 bits; k in bits 16..18
        cv.y = __float_as_int(v);
        sCV[p] = cv;
    }
}

// ---------------- gather: phase-coherent col-blocked SpMM (single pass) -------
// 2048 blocks * 4 waves = 8192 phase waves; wave w owns nodes {k*8192+w : k<7}.
// acc[7][8] fp32 (static idx; k selected by wave-uniform switch from metadata).
// Outer loop over 13 col-blocks: live H window = 4096 rows * 1KB = 4MB (one
// XCD L2; L3 backstops). Each lane loads its 8 dims of a row as ONE uint4
// (1KB/wave-instr); unroll-4 keeps 4 independent loads in flight.
#define ACC8(K)                                             \
    acc[K][0] = fmaf(vv[j], lo16(hv[j].x), acc[K][0]);      \
    acc[K][1] = fmaf(vv[j], hi16(hv[j].x), acc[K][1]);      \
    acc[K][2] = fmaf(vv[j], lo16(hv[j].y), acc[K][2]);      \
    acc[K][3] = fmaf(vv[j], hi16(hv[j].y), acc[K][3]);      \
    acc[K][4] = fmaf(vv[j], lo16(hv[j].z), acc[K][4]);      \
    acc[K][5] = fmaf(vv[j], hi16(hv[j].z), acc[K][5]);      \
    acc[K][6] = fmaf(vv[j], lo16(hv[j].w), acc[K][6]);      \
    acc[K][7] = fmaf(vv[j], hi16(hv[j].w), acc[K][7]);

__global__ __launch_bounds__(256, 4) void gather_kernel(
        const int* __restrict__ start, const int2* __restrict__ sCV,
        const unsigned short* __restrict__ H,
        const void* __restrict__ biasv, void* __restrict__ outv,
        const int* __restrict__ flags) {
    const bool fb = flags[0] != 0;
    const int lane = threadIdx.x & 63;
    const int w = blockIdx.x * 4 + (threadIdx.x >> 6);   // 0..8191
    const unsigned short* Hl = H + lane * 8;             // this lane's 8 dims

    float acc[NK][8];
    #pragma unroll
    for (int k = 0; k < NK; ++k)
        #pragma unroll
        for (int j = 0; j < 8; ++j) acc[k][j] = 0.f;

    for (int cb = 0; cb < NCB; ++cb) {
        const int key = cb * NWAVE + w;
        const int runs = start[key], rune = start[key + 1];

        for (int q0 = runs; q0 < rune; q0 += 64) {
            int idx = q0 + lane;
            int clamped = (idx < rune) ? idx : (rune - 1);
            int2 cv = sCV[clamped];                      // coalesced metadata batch
            int qe = (rune < q0 + 64) ? rune : (q0 + 64);
            for (int q = q0; q < qe; q += 4) {
                uint4 hv[4]; float vv[4]; int kk[4];
                #pragma unroll
                for (int j = 0; j < 4; ++j) {
                    int qq = q + j;
                    bool on = qq < qe;
                    int qc = on ? qq : (qe - 1);
                    int sx = __builtin_amdgcn_readlane(cv.x, qc - q0);  // uniform
                    kk[j] = sx >> 16;
                    vv[j] = on ? __int_as_float(__builtin_amdgcn_readlane(cv.y, qc - q0)) : 0.f;
                    hv[j] = *(const uint4*)(Hl + ((size_t)(sx & 0xffff) << 9));
                }
                #pragma unroll
                for (int j = 0; j < 4; ++j) {
                    switch (kk[j]) {                     // wave-uniform scalar branch
                        case 0: ACC8(0) break;
                        case 1: ACC8(1) break;
                        case 2: ACC8(2) break;
                        case 3: ACC8(3) break;
                        case 4: ACC8(4) break;
                        case 5: ACC8(5) break;
                        default: ACC8(6) break;
                    }
                }
            }
        }
        __syncthreads();   // phase-lock the block's 4 waves
    }

    // epilogue: 8 dims per lane per owned node (+bias)
    float b0, b1, b2, b3, b4, b5, b6, b7;
    if (fb) {
        uint4 bb = *((const uint4*)biasv + lane);
        b0 = lo16(bb.x); b1 = hi16(bb.x); b2 = lo16(bb.y); b3 = hi16(bb.y);
        b4 = lo16(bb.z); b5 = hi16(bb.z); b6 = lo16(bb.w); b7 = hi16(bb.w);
    } else {
        const float4* bp = (const float4*)biasv + lane * 2;
        float4 f0 = bp[0], f1 = bp[1];
        b0 = f0.x; b1 = f0.y; b2 = f0.z; b3 = f0.w;
        b4 = f1.x; b5 = f1.y; b6 = f1.z; b7 = f1.w;
    }
    #pragma unroll
    for (int k = 0; k < NK; ++k) {
        int node = k * NWAVE + w;
        if (node < N_NODES) {
            if (fb) {
                uint4 o;
                o.x = f2bfu(acc[k][0] + b0) | (f2bfu(acc[k][1] + b1) << 16);
                o.y = f2bfu(acc[k][2] + b2) | (f2bfu(acc[k][3] + b3) << 16);
                o.z = f2bfu(acc[k][4] + b4) | (f2bfu(acc[k][5] + b5) << 16);
                o.w = f2bfu(acc[k][6] + b6) | (f2bfu(acc[k][7] + b7) << 16);
                *((uint4*)((unsigned short*)outv + (size_t)node * DIM) + lane) = o;
            } else {
                float4 o0, o1;
                o0.x = acc[k][0] + b0; o0.y = acc[k][1] + b1;
                o0.z = acc[k][2] + b2; o0.w = acc[k][3] + b3;
                o1.x = acc[k][4] + b4; o1.y = acc[k][5] + b5;
                o1.z = acc[k][6] + b6; o1.w = acc[k][7] + b7;
                float4* op = (float4*)((float*)outv + (size_t)node * DIM) + lane * 2;
                op[0] = o0; op[1] = o1;
            }
        }
    }
}

extern "C" void kernel_launch(void* const* d_in, const int* in_sizes, int n_in,
                              void* d_out, int out_size, void* d_ws, size_t ws_size,
                              hipStream_t stream) {
    const void* X    = d_in[0];
    const void* W    = d_in[1];
    const void* bias = d_in[2];
    const void* eval = d_in[3];
    const int*  erow = (const int*)d_in[4];
    const int*  ecol = (const int*)d_in[5];

    char* w = (char*)d_ws;
    size_t o = 0;
    int* flags = (int*)(w + o); o += 256;
    unsigned short* hidden = (unsigned short*)(w + o); o += (size_t)N_NODES * DIM * 2;  // 51.2 MB
    int2*  sCV    = (int2*)(w + o);  o += (size_t)N_EDGES * 8;                          // 12.8 MB
    int*   cnt    = (int*)(w + o);   o += 425984;             // NKEYS ints
    int*   start  = (int*)(w + o);   o += 426240;             // NKEYS+1 ints (padded)
    int*   cursor = (int*)(w + o);   o += 425984;
    unsigned short* Wt = (unsigned short*)(w + o); o += (size_t)DIM * DIM * 2;          // 0.5 MB
    int*   bsum   = (int*)(w + o);   o += 1024;
    size_t base_end = o;
    unsigned short* Xc = (unsigned short*)(w + o);
    size_t need_xc = base_end + (size_t)N_NODES * DIM * 2;                              // +51.2 MB
    const int have_xc = (ws_size >= need_xc) ? 1 : 0;

    hipMemsetAsync(cnt, 0, (size_t)NKEYS * sizeof(int), stream);

    detect_kernel<<<1, 256, 0, stream>>>((const unsigned int*)X, erow, flags);
    if (have_xc)
        convert_x<<<(N_NODES * DIM) / (256 * 8), 256, 0, stream>>>(X, Xc, flags);
    transpose_w<<<dim3(16, 16), dim3(32, 8), 0, stream>>>(W, Wt, flags);
    gemm_kernel<<<dim3(DIM / TN, (N_NODES + TM - 1) / TM), 256, 0, stream>>>(
        X, Xc, have_xc, Wt, hidden, flags);
    hist_kernel<<<(N_EDGES + 255) / 256, 256, 0, stream>>>(erow, ecol, cnt, flags);
    scan1_kernel<<<SCAN_NB, 256, 0, stream>>>(cnt, bsum);
    scan2_kernel<<<1, 256, 0, stream>>>(bsum);
    scan3_kernel<<<SCAN_NB, 256, 0, stream>>>(cnt, bsum, start, cursor);
    scatter_kernel<<<(N_EDGES + 255) / 256, 256, 0, stream>>>(erow, ecol, eval, cursor, sCV, flags);
    gather_kernel<<<NWAVE / 4, 256, 0, stream>>>(start, sCV, hidden, bias, d_out, flags);
}

// Round 7
// 698.438 us; speedup vs baseline: 37.5504x; 37.5504x over previous
//
#include <hip/hip_runtime.h>

typedef short short8 __attribute__((ext_vector_type(8)));
typedef float v4f   __attribute__((ext_vector_type(4)));

#define N_NODES 50000
#define N_EDGES 1600000
#define DIM     512
#define NCB     13        // col blocks: col>>12, 0..12 (4096-row window)
#define NWAVE   4096      // phase-resident waves (1024 blocks * 4) = 16 waves/CU
#define NK      13        // nodes per wave: ceil(50000/4096); k = node>>12
#define NKEYS   692224    // NCB * NWAVE * NK
#define SCAN_NB 676       // 676 * 1024 = 692224 exactly

__device__ __forceinline__ float bf2f(unsigned short u) {
    unsigned int x = ((unsigned int)u) << 16;
    return __uint_as_float(x);
}
__device__ __forceinline__ unsigned int f2bfu(float f) {
    unsigned int x = __float_as_uint(f);
    unsigned int r = x + 0x7fffu + ((x >> 16) & 1u);   // RTNE
    return r >> 16;
}
__device__ __forceinline__ float lo16(unsigned int u) { return __uint_as_float(u << 16); }
__device__ __forceinline__ float hi16(unsigned int u) { return __uint_as_float(u & 0xffff0000u); }

__device__ __forceinline__ int edge_key(int r, int c) {
    // (colblock, waveslot, k): contiguous run per (wave, phase), sub-sorted by k
    return ((c >> 12) * NWAVE + (r & (NWAVE - 1))) * NK + (r >> 12);
}

__device__ __forceinline__ void gload_lds16(const void* g, void* l) {
    __builtin_amdgcn_global_load_lds(
        (const __attribute__((address_space(1))) unsigned int*)g,
        (__attribute__((address_space(3))) unsigned int*)l, 16, 0, 0);
}

// ---------------- dtype detection --------------------------------------------
__global__ void detect_kernel(const unsigned int* __restrict__ xw,
                              const int* __restrict__ erow,
                              int* __restrict__ flags) {
    __shared__ int cbf, cz;
    if (threadIdx.x == 0) { cbf = 0; cz = 0; }
    __syncthreads();
    int lb = 0, lz = 0;
    for (int i = threadIdx.x; i < 1024; i += 256) {
        unsigned int w = xw[i];
        unsigned int e0 = (w >> 7) & 0xFFu;
        unsigned int e1 = (w >> 23) & 0xFFu;
        if (e0 >= 0x70u && e0 <= 0x8Fu && e1 >= 0x70u && e1 <= 0x8Fu) lb++;
        if (erow[2 * i + 1] == 0) lz++;
    }
    atomicAdd(&cbf, lb);
    atomicAdd(&cz, lz);
    __syncthreads();
    if (threadIdx.x == 0) {
        flags[0] = (cbf > 512) ? 1 : 0;
        flags[1] = (cz > 512) ? 1 : 0;
    }
}

// ---------------- X fp32 -> bf16 pre-convert ----------------------------------
__global__ __launch_bounds__(256) void convert_x(const void* __restrict__ Xv,
                                                 unsigned short* __restrict__ Xc,
                                                 const int* __restrict__ flags) {
    if (flags[0] != 0) return;
    const float* Xf = (const float*)Xv;
    size_t i = ((size_t)blockIdx.x * 256 + threadIdx.x) * 8;
    float4 f0 = *(const float4*)(Xf + i);
    float4 f1 = *(const float4*)(Xf + i + 4);
    uint4 o;
    o.x = f2bfu(f0.x) | (f2bfu(f0.y) << 16);
    o.y = f2bfu(f0.z) | (f2bfu(f0.w) << 16);
    o.z = f2bfu(f1.x) | (f2bfu(f1.y) << 16);
    o.w = f2bfu(f1.z) | (f2bfu(f1.w) << 16);
    *(uint4*)(Xc + i) = o;
}

// ---------------- W transpose -> canonical bf16 Wt[n][k] = W[k][n] ------------
__global__ void transpose_w(const void* __restrict__ Wv,
                            unsigned short* __restrict__ Wt,
                            const int* __restrict__ flags) {
    __shared__ unsigned short tile[32][33];
    const bool fb = flags[0] != 0;
    int bx = blockIdx.x * 32, by = blockIdx.y * 32;
    int tx = threadIdx.x, ty = threadIdx.y;
    if (fb) {
        const unsigned short* W = (const unsigned short*)Wv;
        for (int r = ty; r < 32; r += 8)
            tile[r][tx] = W[(by + r) * DIM + bx + tx];
    } else {
        const float* W = (const float*)Wv;
        for (int r = ty; r < 32; r += 8)
            tile[r][tx] = (unsigned short)f2bfu(W[(by + r) * DIM + bx + tx]);
    }
    __syncthreads();
    for (int r = ty; r < 32; r += 8)
        Wt[(bx + r) * DIM + by + tx] = tile[tx][r];
}

// ---------------- GEMM: hidden = X @ W  (m97 structure: global_load_lds) ------
#define TM 128
#define TN 128
#define BK 32

__global__ __launch_bounds__(256) void gemm_kernel(
        const void* __restrict__ Xv,
        const unsigned short* __restrict__ Xc,
        const int have_xc,
        const unsigned short* __restrict__ Wt,
        unsigned short* __restrict__ H,
        const int* __restrict__ flags) {
    __shared__ unsigned short lA[TM * BK];
    __shared__ unsigned short lB[TN * BK];

    const bool fb = flags[0] != 0;
    const bool bfp = fb || (have_xc != 0);
    const unsigned short* Xb = fb ? (const unsigned short*)Xv : Xc;
    const float*          Xf = (const float*)Xv;

    const int t = threadIdx.x;
    const int mBase = blockIdx.y * TM;
    const int nBase = blockIdx.x * TN;
    const int w = t >> 6, lane = t & 63;
    const int lr = lane & 15, quad = lane >> 4;
    const int wr = w >> 1, wc = w & 1;

    v4f acc[4][4];
    #pragma unroll
    for (int i = 0; i < 4; ++i)
        #pragma unroll
        for (int j = 0; j < 4; ++j) acc[i][j] = (v4f)0.0f;

    for (int k0 = 0; k0 < DIM; k0 += BK) {
        #pragma unroll
        for (int r = 0; r < 2; ++r) {
            int chunk = w * 2 + r;
            int row = chunk * 16 + (lane >> 2);
            const unsigned short* gB = Wt + (size_t)(nBase + row) * DIM + k0 + (lane & 3) * 8;
            gload_lds16(gB, lB + chunk * 512);
        }
        if (bfp) {
            #pragma unroll
            for (int r = 0; r < 2; ++r) {
                int chunk = w * 2 + r;
                int row = chunk * 16 + (lane >> 2);
                int grow = mBase + row; if (grow >= N_NODES) grow = N_NODES - 1;
                const unsigned short* gA = Xb + (size_t)grow * DIM + k0 + (lane & 3) * 8;
                gload_lds16(gA, lA + chunk * 512);
            }
        } else {
            #pragma unroll
            for (int rep = 0; rep < 2; ++rep) {
                int idx = rep * 256 + t;
                int r = idx >> 2;
                int cc = (idx & 3) * 8;
                int grow = mBase + r; if (grow >= N_NODES) grow = N_NODES - 1;
                size_t goff = (size_t)grow * DIM + k0 + cc;
                float4 a0 = *(const float4*)(Xf + goff);
                float4 a1 = *(const float4*)(Xf + goff + 4);
                uint4 av;
                av.x = f2bfu(a0.x) | (f2bfu(a0.y) << 16);
                av.y = f2bfu(a0.z) | (f2bfu(a0.w) << 16);
                av.z = f2bfu(a1.x) | (f2bfu(a1.y) << 16);
                av.w = f2bfu(a1.z) | (f2bfu(a1.w) << 16);
                *(uint4*)(&lA[r * BK + cc]) = av;
            }
        }
        __syncthreads();

        short8 bfr[4];
        #pragma unroll
        for (int j = 0; j < 4; ++j)
            bfr[j] = *(const short8*)(&lB[(wc * 64 + j * 16 + lr) * BK + quad * 8]);
        #pragma unroll
        for (int i = 0; i < 4; ++i) {
            short8 a = *(const short8*)(&lA[(wr * 64 + i * 16 + lr) * BK + quad * 8]);
            #pragma unroll
            for (int j = 0; j < 4; ++j)
                acc[i][j] = __builtin_amdgcn_mfma_f32_16x16x32_bf16(a, bfr[j], acc[i][j], 0, 0, 0);
        }
        __syncthreads();
    }

    #pragma unroll
    for (int i = 0; i < 4; ++i) {
        #pragma unroll
        for (int j = 0; j < 4; ++j) {
            #pragma unroll
            for (int r = 0; r < 4; ++r) {
                int gm = mBase + wr * 64 + i * 16 + quad * 4 + r;
                int gn = nBase + wc * 64 + j * 16 + lr;
                if (gm < N_NODES)
                    H[(size_t)gm * DIM + gn] = (unsigned short)f2bfu(acc[i][j][r]);
            }
        }
    }
}

// ---------------- counting sort on key=(cb, waveslot, k) ----------------------
__global__ void hist_kernel(const int* __restrict__ row, const int* __restrict__ col,
                            int* __restrict__ cnt,
                            const int* __restrict__ flags) {
    const bool f64 = flags[1] != 0;
    int i = blockIdx.x * 256 + threadIdx.x;
    if (i < N_EDGES) {
        int r = f64 ? ((const int2*)row)[i].x : row[i];
        int c = f64 ? ((const int2*)col)[i].x : col[i];
        atomicAdd(&cnt[edge_key(r, c)], 1);
    }
}

__global__ __launch_bounds__(256) void scan1_kernel(const int* __restrict__ cnt,
                                                    int* __restrict__ bsum) {
    __shared__ int sh[256];
    const int b = blockIdx.x, t = threadIdx.x;
    int base = b * 1024 + t * 4;
    int s = 0;
    #pragma unroll
    for (int k = 0; k < 4; ++k) {
        int i = base + k;
        if (i < NKEYS) s += cnt[i];
    }
    sh[t] = s;
    __syncthreads();
    for (int off = 128; off > 0; off >>= 1) {
        if (t < off) sh[t] += sh[t + off];
        __syncthreads();
    }
    if (t == 0) bsum[b] = sh[0];
}

// scan2: exclusive prefix over the 676 block sums (single block, 3/thread)
__global__ __launch_bounds__(256) void scan2_kernel(int* __restrict__ bsum) {
    __shared__ int sh[256];
    const int t = threadIdx.x;
    int i0 = t * 3;
    int v0 = (i0     < SCAN_NB) ? bsum[i0]     : 0;
    int v1 = (i0 + 1 < SCAN_NB) ? bsum[i0 + 1] : 0;
    int v2 = (i0 + 2 < SCAN_NB) ? bsum[i0 + 2] : 0;
    int s = v0 + v1 + v2;
    sh[t] = s;
    __syncthreads();
    for (int off = 1; off < 256; off <<= 1) {
        int x = (t >= off) ? sh[t - off] : 0;
        __syncthreads();
        sh[t] += x;
        __syncthreads();
    }
    int excl = sh[t] - s;
    if (i0     < SCAN_NB) bsum[i0]     = excl;
    if (i0 + 1 < SCAN_NB) bsum[i0 + 1] = excl + v0;
    if (i0 + 2 < SCAN_NB) bsum[i0 + 2] = excl + v0 + v1;
}

__global__ __launch_bounds__(256) void scan3_kernel(const int* __restrict__ cnt,
                                                    const int* __restrict__ bsum,
                                                    int* __restrict__ start,
                                                    int* __restrict__ cursor) {
    __shared__ int sh[256];
    const int b = blockIdx.x, t = threadIdx.x;
    if (b == 0 && t == 0) start[NKEYS] = N_EDGES;
    int boffs = bsum[b];
    int base = b * 1024 + t * 4;
    int v[4];
    #pragma unroll
    for (int k = 0; k < 4; ++k) {
        int i = base + k;
        v[k] = (i < NKEYS) ? cnt[i] : 0;
    }
    int tsum = v[0] + v[1] + v[2] + v[3];
    sh[t] = tsum;
    __syncthreads();
    for (int off = 1; off < 256; off <<= 1) {
        int x = (t >= off) ? sh[t - off] : 0;
        __syncthreads();
        sh[t] += x;
        __syncthreads();
    }
    int excl = sh[t] - tsum + boffs;
    #pragma unroll
    for (int k = 0; k < 4; ++k) {
        int i = base + k;
        if (i < NKEYS) { start[i] = excl; cursor[i] = excl; }
        excl += v[k];
    }
}

__global__ void scatter_kernel(const int* __restrict__ row, const int* __restrict__ col,
                               const void* __restrict__ valv,
                               int* __restrict__ cursor,
                               int2* __restrict__ sCV,
                               const int* __restrict__ flags) {
    const bool fb  = flags[0] != 0;
    const bool f64 = flags[1] != 0;
    int i = blockIdx.x * 256 + threadIdx.x;
    if (i < N_EDGES) {
        int r = f64 ? ((const int2*)row)[i].x : row[i];
        int c = f64 ? ((const int2*)col)[i].x : col[i];
        float v = fb ? bf2f(((const unsigned short*)valv)[i])
                     : ((const float*)valv)[i];
        int p = atomicAdd(&cursor[edge_key(r, c)], 1);
        int2 cv; cv.x = c; cv.y = __float_as_int(v);
        sCV[p] = cv;
    }
}

// ---------------- gather: phase-coherent col-blocked SpMM ---------------------
// Round-3 proven skeleton (1024 blocks * 4 waves, NK=13 per-k static segments,
// two dim-passes, acc[13][4] static-indexed -> registers, no spill) with ONE
// change: edges processed in unroll-4 predicated groups -> 4 independent uint2
// row loads in flight before the fmas (restores MLP lost to the serial chain).
__global__ __launch_bounds__(256, 4) void gather_kernel(
        const int* __restrict__ start, const int2* __restrict__ sCV,
        const unsigned short* __restrict__ H,
        const void* __restrict__ biasv, void* __restrict__ outv,
        const int* __restrict__ flags, const int pass) {
    const bool fb = flags[0] != 0;
    const int lane = threadIdx.x & 63;
    const int w = blockIdx.x * 4 + (threadIdx.x >> 6);   // 0..4095
    const int d0 = pass * 256 + lane * 4;                // this lane's 4 dims
    const unsigned short* Hd = H + d0;

    float acc[NK][4];
    #pragma unroll
    for (int k = 0; k < NK; ++k)
        #pragma unroll
        for (int j = 0; j < 4; ++j) acc[k][j] = 0.f;

    for (int cb = 0; cb < NCB; ++cb) {
        int rbase = (cb * NWAVE + w) * NK;
        int b[NK + 1];
        #pragma unroll
        for (int i = 0; i <= NK; ++i) b[i] = start[rbase + i];
        int runs = b[0], rune = b[NK];

        for (int q0 = runs; q0 < rune; q0 += 64) {
            int idx = q0 + lane;
            int clamped = (idx < rune) ? idx : (rune - 1);
            int2 cv = sCV[clamped];                      // coalesced metadata batch
            int qe = (rune < q0 + 64) ? rune : (q0 + 64);
            #pragma unroll
            for (int k = 0; k < NK; ++k) {
                int lo = (b[k]     > q0) ? b[k]     : q0;
                int hi = (b[k + 1] < qe) ? b[k + 1] : qe;
                for (int q = lo; q < hi; q += 4) {
                    uint2 hv[4]; float vv[4];
                    #pragma unroll
                    for (int j = 0; j < 4; ++j) {
                        int qq = q + j;
                        bool on = qq < hi;
                        int qc = on ? qq : (hi - 1);
                        int col = __builtin_amdgcn_readlane(cv.x, qc - q0);  // uniform
                        vv[j] = on ? __int_as_float(__builtin_amdgcn_readlane(cv.y, qc - q0)) : 0.f;
                        hv[j] = *(const uint2*)(Hd + ((size_t)(unsigned)col << 9));
                    }
                    #pragma unroll
                    for (int j = 0; j < 4; ++j) {
                        acc[k][0] = fmaf(vv[j], lo16(hv[j].x), acc[k][0]);
                        acc[k][1] = fmaf(vv[j], hi16(hv[j].x), acc[k][1]);
                        acc[k][2] = fmaf(vv[j], lo16(hv[j].y), acc[k][2]);
                        acc[k][3] = fmaf(vv[j], hi16(hv[j].y), acc[k][3]);
                    }
                }
            }
        }
        __syncthreads();   // phase-lock the block's 4 waves
    }

    // epilogue: write 4 dims per owned node (+bias)
    float b0, b1, b2, b3;
    if (fb) {
        uint2 bb = *(const uint2*)((const unsigned short*)biasv + d0);
        b0 = lo16(bb.x); b1 = hi16(bb.x); b2 = lo16(bb.y); b3 = hi16(bb.y);
    } else {
        const float* bp = (const float*)biasv + d0;
        b0 = bp[0]; b1 = bp[1]; b2 = bp[2]; b3 = bp[3];
    }
    #pragma unroll
    for (int k = 0; k < NK; ++k) {
        int node = k * NWAVE + w;
        if (node < N_NODES) {
            if (fb) {
                uint2 o;
                o.x = f2bfu(acc[k][0] + b0) | (f2bfu(acc[k][1] + b1) << 16);
                o.y = f2bfu(acc[k][2] + b2) | (f2bfu(acc[k][3] + b3) << 16);
                *(uint2*)((unsigned short*)outv + (size_t)node * DIM + d0) = o;
            } else {
                float4 o;
                o.x = acc[k][0] + b0; o.y = acc[k][1] + b1;
                o.z = acc[k][2] + b2; o.w = acc[k][3] + b3;
                *(float4*)((float*)outv + (size_t)node * DIM + d0) = o;
            }
        }
    }
}

extern "C" void kernel_launch(void* const* d_in, const int* in_sizes, int n_in,
                              void* d_out, int out_size, void* d_ws, size_t ws_size,
                              hipStream_t stream) {
    const void* X    = d_in[0];
    const void* W    = d_in[1];
    const void* bias = d_in[2];
    const void* eval = d_in[3];
    const int*  erow = (const int*)d_in[4];
    const int*  ecol = (const int*)d_in[5];

    char* w = (char*)d_ws;
    size_t o = 0;
    int* flags = (int*)(w + o); o += 256;
    unsigned short* hidden = (unsigned short*)(w + o); o += (size_t)N_NODES * DIM * 2;  // 51.2 MB
    int2*  sCV    = (int2*)(w + o);  o += (size_t)N_EDGES * 8;                          // 12.8 MB
    int*   cnt    = (int*)(w + o);   o += 2769152;            // NKEYS ints (padded)
    int*   start  = (int*)(w + o);   o += 2769152;            // NKEYS+1 ints (padded)
    int*   cursor = (int*)(w + o);   o += 2769152;
    unsigned short* Wt = (unsigned short*)(w + o); o += (size_t)DIM * DIM * 2;          // 0.5 MB
    int*   bsum   = (int*)(w + o);   o += 4096;
    size_t base_end = o;
    unsigned short* Xc = (unsigned short*)(w + o);
    size_t need_xc = base_end + (size_t)N_NODES * DIM * 2;                              // +51.2 MB
    const int have_xc = (ws_size >= need_xc) ? 1 : 0;

    hipMemsetAsync(cnt, 0, (size_t)NKEYS * sizeof(int), stream);

    detect_kernel<<<1, 256, 0, stream>>>((const unsigned int*)X, erow, flags);
    if (have_xc)
        convert_x<<<(N_NODES * DIM) / (256 * 8), 256, 0, stream>>>(X, Xc, flags);
    transpose_w<<<dim3(16, 16), dim3(32, 8), 0, stream>>>(W, Wt, flags);
    gemm_kernel<<<dim3(DIM / TN, (N_NODES + TM - 1) / TM), 256, 0, stream>>>(
        X, Xc, have_xc, Wt, hidden, flags);
    hist_kernel<<<(N_EDGES + 255) / 256, 256, 0, stream>>>(erow, ecol, cnt, flags);
    scan1_kernel<<<SCAN_NB, 256, 0, stream>>>(cnt, bsum);
    scan2_kernel<<<1, 256, 0, stream>>>(bsum);
    scan3_kernel<<<SCAN_NB, 256, 0, stream>>>(cnt, bsum, start, cursor);
    scatter_kernel<<<(N_EDGES + 255) / 256, 256, 0, stream>>>(erow, ecol, eval, cursor, sCV, flags);
    gather_kernel<<<NWAVE / 4, 256, 0, stream>>>(start, sCV, hidden, bias, d_out, flags, 0);
    gather_kernel<<<NWAVE / 4, 256, 0, stream>>>(start, sCV, hidden, bias, d_out, flags, 1);
}